// Round 1
// baseline (1842.060 us; speedup 1.0000x reference)
//
#include <hip/hip_runtime.h>

#define IN_DIM 128
#define HID_DIM 256
#define OUT_DIM 128
#define KHOPS 10

// ---------------- CSR build ----------------

__global__ void count_init(int* __restrict__ cnt, int* __restrict__ fill, int N) {
    int i = blockIdx.x * blockDim.x + threadIdx.x;
    if (i < N) { cnt[i] = 0; fill[i] = 0; }
}

__global__ void count_edges(const int* __restrict__ dst, int* __restrict__ cnt, int E) {
    int e = blockIdx.x * blockDim.x + threadIdx.x;
    if (e < E) atomicAdd(&cnt[dst[e]], 1);
}

__global__ void norm_kernel(const int* __restrict__ cnt, float* __restrict__ norm, int N) {
    int i = blockIdx.x * blockDim.x + threadIdx.x;
    if (i < N) {
        float deg = (float)(cnt[i] + 1);   // +1 self loop, always >= 1
        norm[i] = rsqrtf(deg);
    }
}

__global__ void scan_block(const int* __restrict__ cnt, int* __restrict__ row_ptr,
                           int* __restrict__ bsum, int N) {
    __shared__ int s[256];
    int tid = threadIdx.x;
    int gid = blockIdx.x * 256 + tid;
    int v = (gid < N) ? cnt[gid] : 0;
    s[tid] = v;
    __syncthreads();
    for (int off = 1; off < 256; off <<= 1) {
        int t = (tid >= off) ? s[tid - off] : 0;
        __syncthreads();
        s[tid] += t;
        __syncthreads();
    }
    if (gid < N) row_ptr[gid] = s[tid] - v;   // local exclusive
    if (tid == 255) bsum[blockIdx.x] = s[255];
}

__global__ void scan_top(int* __restrict__ bsum, int nb) {
    __shared__ int s[512];
    int tid = threadIdx.x;
    int v = (tid < nb) ? bsum[tid] : 0;
    s[tid] = v;
    __syncthreads();
    for (int off = 1; off < 512; off <<= 1) {
        int t = (tid >= off) ? s[tid - off] : 0;
        __syncthreads();
        s[tid] += t;
        __syncthreads();
    }
    if (tid < nb) bsum[tid] = s[tid] - v;     // exclusive
}

__global__ void scan_add(int* __restrict__ row_ptr, const int* __restrict__ bsum,
                         int N, int E) {
    int gid = blockIdx.x * 256 + threadIdx.x;
    if (gid < N) row_ptr[gid] += bsum[blockIdx.x];
    if (gid == 0) row_ptr[N] = E;
}

__global__ void fill_csr(const int* __restrict__ src, const int* __restrict__ dst,
                         const int* __restrict__ row_ptr, int* __restrict__ fill,
                         int* __restrict__ col, int E) {
    int e = blockIdx.x * blockDim.x + threadIdx.x;
    if (e < E) {
        int d = dst[e];
        int p = atomicAdd(&fill[d], 1);
        col[row_ptr[d] + p] = src[e];
    }
}

// ---------------- propagation ----------------

// g = norm * h.  init: g0 = norm * feat
__global__ void init_g(const float* __restrict__ feat, const float* __restrict__ norm,
                       float* __restrict__ g, int N) {
    int idx = blockIdx.x * blockDim.x + threadIdx.x;   // one float4 per thread
    int total = N * (IN_DIM / 4);
    if (idx >= total) return;
    int row = idx / (IN_DIM / 4);
    float nr = norm[row];
    float4 v = *(const float4*)(feat + (size_t)idx * 4);
    v.x *= nr; v.y *= nr; v.z *= nr; v.w *= nr;
    *(float4*)(g + (size_t)idx * 4) = v;
}

// one 64-lane wave per dst node; lane owns dims [2*lane, 2*lane+1]
// g_out[d] = 0.9*norm[d]^2 * (g_in[d] + sum_{s in N(d)} g_in[s]) + 0.1*norm[d]*feat[d]
__global__ void hop_kernel(const float* __restrict__ g_in, float* __restrict__ g_out,
                           const float* __restrict__ feat, const float* __restrict__ norm,
                           const int* __restrict__ row_ptr, const int* __restrict__ col,
                           int N) {
    int gid  = blockIdx.x * blockDim.x + threadIdx.x;
    int node = gid >> 6;
    int lane = gid & 63;
    if (node >= N) return;
    size_t base = (size_t)node * IN_DIM + lane * 2;
    float2 acc = *(const float2*)(g_in + base);        // self loop
    int beg = row_ptr[node], end = row_ptr[node + 1];
    int e = beg;
    for (; e + 1 < end; e += 2) {
        int s0 = col[e], s1 = col[e + 1];
        float2 v0 = *(const float2*)(g_in + (size_t)s0 * IN_DIM + lane * 2);
        float2 v1 = *(const float2*)(g_in + (size_t)s1 * IN_DIM + lane * 2);
        acc.x += v0.x + v1.x;
        acc.y += v0.y + v1.y;
    }
    if (e < end) {
        int s0 = col[e];
        float2 v0 = *(const float2*)(g_in + (size_t)s0 * IN_DIM + lane * 2);
        acc.x += v0.x;
        acc.y += v0.y;
    }
    float nr = norm[node];
    float c1 = 0.9f * nr * nr;
    float c2 = 0.1f * nr;
    float2 f = *(const float2*)(feat + base);
    float2 o;
    o.x = c1 * acc.x + c2 * f.x;
    o.y = c1 * acc.y + c2 * f.y;
    *(float2*)(g_out + base) = o;
}

// ---------------- fused MLP ----------------
// out = relu(h @ W1 + b1) @ W2 + b2,  h = g / norm
// block: 256 threads, 64 node-rows per block

__global__ __launch_bounds__(256) void mlp_fused(
    const float* __restrict__ g, const float* __restrict__ norm,
    const float* __restrict__ W1, const float* __restrict__ b1,
    const float* __restrict__ W2, const float* __restrict__ b2,
    float* __restrict__ out, int N)
{
    __shared__ float Ah[64][IN_DIM + 1];    // pad -> 2-way max on reads
    __shared__ float Hid[64][HID_DIM + 1];
    int tid  = threadIdx.x;
    int row0 = blockIdx.x * 64;

    // load A tile: h = g * (1/norm)
    for (int i = tid; i < 64 * (IN_DIM / 4); i += 256) {
        int r = i >> 5;            // IN_DIM/4 = 32 float4 per row
        int c = (i & 31) << 2;
        int row = row0 + r;
        float4 v = {0.f, 0.f, 0.f, 0.f};
        if (row < N) {
            v = *(const float4*)(g + (size_t)row * IN_DIM + c);
            float inv = 1.0f / norm[row];
            v.x *= inv; v.y *= inv; v.z *= inv; v.w *= inv;
        }
        Ah[r][c + 0] = v.x; Ah[r][c + 1] = v.y; Ah[r][c + 2] = v.z; Ah[r][c + 3] = v.w;
    }
    __syncthreads();

    int ty = tid >> 4;     // 0..15 -> 4 rows each
    int tx = tid & 15;     // 0..15 -> 4 cols each (per chunk)

    // GEMM1: Hid = relu(Ah @ W1 + b1), HID in 4 chunks of 64 cols
    for (int ch = 0; ch < 4; ++ch) {
        int colbase = ch * 64 + tx * 4;
        float acc[4][4];
        #pragma unroll
        for (int i = 0; i < 4; ++i)
            #pragma unroll
            for (int j = 0; j < 4; ++j) acc[i][j] = 0.f;

        for (int k = 0; k < IN_DIM; ++k) {
            float4 b = *(const float4*)(W1 + (size_t)k * HID_DIM + colbase);
            #pragma unroll
            for (int i = 0; i < 4; ++i) {
                float a = Ah[ty * 4 + i][k];
                acc[i][0] += a * b.x;
                acc[i][1] += a * b.y;
                acc[i][2] += a * b.z;
                acc[i][3] += a * b.w;
            }
        }
        float4 bias = *(const float4*)(b1 + colbase);
        #pragma unroll
        for (int i = 0; i < 4; ++i) {
            float r0 = acc[i][0] + bias.x;
            float r1 = acc[i][1] + bias.y;
            float r2 = acc[i][2] + bias.z;
            float r3 = acc[i][3] + bias.w;
            Hid[ty * 4 + i][colbase + 0] = r0 > 0.f ? r0 : 0.f;
            Hid[ty * 4 + i][colbase + 1] = r1 > 0.f ? r1 : 0.f;
            Hid[ty * 4 + i][colbase + 2] = r2 > 0.f ? r2 : 0.f;
            Hid[ty * 4 + i][colbase + 3] = r3 > 0.f ? r3 : 0.f;
        }
    }
    __syncthreads();

    // GEMM2: out = Hid @ W2 + b2 ; each thread: 4 rows x 8 cols
    float acc2[4][8];
    #pragma unroll
    for (int i = 0; i < 4; ++i)
        #pragma unroll
        for (int j = 0; j < 8; ++j) acc2[i][j] = 0.f;

    int cb2 = tx * 8;
    for (int k = 0; k < HID_DIM; ++k) {
        float4 blo = *(const float4*)(W2 + (size_t)k * OUT_DIM + cb2);
        float4 bhi = *(const float4*)(W2 + (size_t)k * OUT_DIM + cb2 + 4);
        #pragma unroll
        for (int i = 0; i < 4; ++i) {
            float a = Hid[ty * 4 + i][k];
            acc2[i][0] += a * blo.x;
            acc2[i][1] += a * blo.y;
            acc2[i][2] += a * blo.z;
            acc2[i][3] += a * blo.w;
            acc2[i][4] += a * bhi.x;
            acc2[i][5] += a * bhi.y;
            acc2[i][6] += a * bhi.z;
            acc2[i][7] += a * bhi.w;
        }
    }
    float4 b2lo = *(const float4*)(b2 + cb2);
    float4 b2hi = *(const float4*)(b2 + cb2 + 4);
    #pragma unroll
    for (int i = 0; i < 4; ++i) {
        int row = row0 + ty * 4 + i;
        if (row < N) {
            float4 olo, ohi;
            olo.x = acc2[i][0] + b2lo.x;
            olo.y = acc2[i][1] + b2lo.y;
            olo.z = acc2[i][2] + b2lo.z;
            olo.w = acc2[i][3] + b2lo.w;
            ohi.x = acc2[i][4] + b2hi.x;
            ohi.y = acc2[i][5] + b2hi.y;
            ohi.z = acc2[i][6] + b2hi.z;
            ohi.w = acc2[i][7] + b2hi.w;
            *(float4*)(out + (size_t)row * OUT_DIM + cb2)     = olo;
            *(float4*)(out + (size_t)row * OUT_DIM + cb2 + 4) = ohi;
        }
    }
}

// ---------------- launch ----------------

extern "C" void kernel_launch(void* const* d_in, const int* in_sizes, int n_in,
                              void* d_out, int out_size, void* d_ws, size_t ws_size,
                              hipStream_t stream) {
    const float* feat = (const float*)d_in[0];
    const float* W1   = (const float*)d_in[1];
    const float* b1   = (const float*)d_in[2];
    const float* W2   = (const float*)d_in[3];
    const float* b2   = (const float*)d_in[4];
    const int*   src  = (const int*)d_in[5];
    const int*   dst  = (const int*)d_in[6];
    float* out = (float*)d_out;

    int N = in_sizes[0] / IN_DIM;     // 100000
    int E = in_sizes[5];              // 1600000

    // workspace carve (256B aligned)
    size_t off = 0;
    auto carve = [&](size_t bytes) -> void* {
        void* p = (char*)d_ws + off;
        off += (bytes + 255) & ~(size_t)255;
        return p;
    };
    float* norm    = (float*)carve((size_t)N * 4);
    int*   cnt     = (int*)carve((size_t)N * 4);
    int*   row_ptr = (int*)carve((size_t)(N + 1) * 4);
    int*   fill    = (int*)carve((size_t)N * 4);
    int*   bsum    = (int*)carve(512 * 4);
    int*   col     = (int*)carve((size_t)E * 4);
    float* gws     = (float*)carve((size_t)N * IN_DIM * 4);
    (void)ws_size;

    int nbN = (N + 255) / 256;        // 391
    int nbE = (E + 255) / 256;        // 6250

    count_init<<<nbN, 256, 0, stream>>>(cnt, fill, N);
    count_edges<<<nbE, 256, 0, stream>>>(dst, cnt, E);
    norm_kernel<<<nbN, 256, 0, stream>>>(cnt, norm, N);
    scan_block<<<nbN, 256, 0, stream>>>(cnt, row_ptr, bsum, N);
    scan_top<<<1, 512, 0, stream>>>(bsum, nbN);
    scan_add<<<nbN, 256, 0, stream>>>(row_ptr, bsum, N, E);
    fill_csr<<<nbE, 256, 0, stream>>>(src, dst, row_ptr, fill, col, E);

    int nbG = (N * (IN_DIM / 4) + 255) / 256;
    init_g<<<nbG, 256, 0, stream>>>(feat, norm, gws, N);

    int nbHop = (N * 64 + 255) / 256;  // one wave per node
    for (int t = 0; t < KHOPS; ++t) {
        const float* gi = (t % 2 == 0) ? gws : out;
        float*       go = (t % 2 == 0) ? out : gws;
        hop_kernel<<<nbHop, 256, 0, stream>>>(gi, go, feat, norm, row_ptr, col, N);
    }
    // after 10 hops (even), final g is in gws

    int nbM = (N + 63) / 64;
    mlp_fused<<<nbM, 256, 0, stream>>>(gws, norm, W1, b1, W2, b2, out, N);
}

// Round 2
// 1693.295 us; speedup vs baseline: 1.0879x; 1.0879x over previous
//
#include <hip/hip_runtime.h>

#define IN_DIM 128
#define HID_DIM 256
#define OUT_DIM 128
#define KHOPS 10

// ---------------- CSR build ----------------

__global__ void count_init(int* __restrict__ cnt, int* __restrict__ fill, int N) {
    int i = blockIdx.x * blockDim.x + threadIdx.x;
    if (i < N) { cnt[i] = 0; fill[i] = 0; }
}

__global__ void count_edges(const int* __restrict__ dst, int* __restrict__ cnt, int E) {
    int e = blockIdx.x * blockDim.x + threadIdx.x;
    if (e < E) atomicAdd(&cnt[dst[e]], 1);
}

__global__ void norm_kernel(const int* __restrict__ cnt, float* __restrict__ norm, int N) {
    int i = blockIdx.x * blockDim.x + threadIdx.x;
    if (i < N) {
        float deg = (float)(cnt[i] + 1);   // +1 self loop, always >= 1
        norm[i] = rsqrtf(deg);
    }
}

__global__ void scan_block(const int* __restrict__ cnt, int* __restrict__ row_ptr,
                           int* __restrict__ bsum, int N) {
    __shared__ int s[256];
    int tid = threadIdx.x;
    int gid = blockIdx.x * 256 + tid;
    int v = (gid < N) ? cnt[gid] : 0;
    s[tid] = v;
    __syncthreads();
    for (int off = 1; off < 256; off <<= 1) {
        int t = (tid >= off) ? s[tid - off] : 0;
        __syncthreads();
        s[tid] += t;
        __syncthreads();
    }
    if (gid < N) row_ptr[gid] = s[tid] - v;   // local exclusive
    if (tid == 255) bsum[blockIdx.x] = s[255];
}

__global__ void scan_top(int* __restrict__ bsum, int nb) {
    __shared__ int s[512];
    int tid = threadIdx.x;
    int v = (tid < nb) ? bsum[tid] : 0;
    s[tid] = v;
    __syncthreads();
    for (int off = 1; off < 512; off <<= 1) {
        int t = (tid >= off) ? s[tid - off] : 0;
        __syncthreads();
        s[tid] += t;
        __syncthreads();
    }
    if (tid < nb) bsum[tid] = s[tid] - v;     // exclusive
}

__global__ void scan_add(int* __restrict__ row_ptr, const int* __restrict__ bsum,
                         int N, int E) {
    int gid = blockIdx.x * 256 + threadIdx.x;
    if (gid < N) row_ptr[gid] += bsum[blockIdx.x];
    if (gid == 0) row_ptr[N] = E;
}

__global__ void fill_csr(const int* __restrict__ src, const int* __restrict__ dst,
                         const int* __restrict__ row_ptr, int* __restrict__ fill,
                         int* __restrict__ col, int E) {
    int e = blockIdx.x * blockDim.x + threadIdx.x;
    if (e < E) {
        int d = dst[e];
        int p = atomicAdd(&fill[d], 1);
        col[row_ptr[d] + p] = src[e];
    }
}

// ---------------- propagation ----------------

// g = norm * h.  init: g0 = norm * feat
__global__ void init_g(const float* __restrict__ feat, const float* __restrict__ norm,
                       float* __restrict__ g, int N) {
    int idx = blockIdx.x * blockDim.x + threadIdx.x;   // one float4 per thread
    int total = N * (IN_DIM / 4);
    if (idx >= total) return;
    int row = idx / (IN_DIM / 4);
    float nr = norm[row];
    float4 v = *(const float4*)(feat + (size_t)idx * 4);
    v.x *= nr; v.y *= nr; v.z *= nr; v.w *= nr;
    *(float4*)(g + (size_t)idx * 4) = v;
}

// half-wave (32 lanes) per dst node; lane owns 4 dims (float4, 16B = sweet spot)
// g_out[d] = 0.9*norm[d]^2 * (g_in[d] + sum_{s in N(d)} g_in[s]) + 0.1*norm[d]*feat[d]
__global__ void hop_kernel(const float* __restrict__ g_in, float* __restrict__ g_out,
                           const float* __restrict__ feat, const float* __restrict__ norm,
                           const int* __restrict__ row_ptr, const int* __restrict__ col,
                           int N) {
    int gid  = blockIdx.x * blockDim.x + threadIdx.x;
    int wave = gid >> 6;
    int lane = gid & 63;
    int half = lane >> 5;          // 0/1: two nodes per wave
    int l    = lane & 31;          // dim-quad index
    int node = wave * 2 + half;
    if (node >= N) return;
    size_t base = (size_t)node * IN_DIM + l * 4;
    float4 acc = *(const float4*)(g_in + base);        // self loop
    int beg = row_ptr[node], end = row_ptr[node + 1];
    int e = beg;
    for (; e + 1 < end; e += 2) {
        int s0 = col[e], s1 = col[e + 1];
        float4 v0 = *(const float4*)(g_in + (size_t)s0 * IN_DIM + l * 4);
        float4 v1 = *(const float4*)(g_in + (size_t)s1 * IN_DIM + l * 4);
        acc.x += v0.x + v1.x;
        acc.y += v0.y + v1.y;
        acc.z += v0.z + v1.z;
        acc.w += v0.w + v1.w;
    }
    if (e < end) {
        int s0 = col[e];
        float4 v0 = *(const float4*)(g_in + (size_t)s0 * IN_DIM + l * 4);
        acc.x += v0.x; acc.y += v0.y; acc.z += v0.z; acc.w += v0.w;
    }
    float nr = norm[node];
    float c1 = 0.9f * nr * nr;
    float c2 = 0.1f * nr;
    float4 f = *(const float4*)(feat + base);
    float4 o;
    o.x = c1 * acc.x + c2 * f.x;
    o.y = c1 * acc.y + c2 * f.y;
    o.z = c1 * acc.z + c2 * f.z;
    o.w = c1 * acc.w + c2 * f.w;
    *(float4*)(g_out + base) = o;
}

// ---------------- fused MLP ----------------
// out = relu(h @ W1 + b1) @ W2 + b2,  h = g / norm
// block: 256 threads, 64 node-rows per block.
// Hid is processed in 4 chunks of 64 cols, reusing a small LDS buffer so
// LDS = 33KB + 17KB = 50.4KB -> 3 blocks/CU (vs 98.8KB -> 1 block/CU before).

__global__ __launch_bounds__(256) void mlp_fused(
    const float* __restrict__ g, const float* __restrict__ norm,
    const float* __restrict__ W1, const float* __restrict__ b1,
    const float* __restrict__ W2, const float* __restrict__ b2,
    float* __restrict__ out, int N)
{
    __shared__ float Ah[64][IN_DIM + 1];    // 33024 B
    __shared__ float Hc[64][68];            // 17408 B, one 64-col hid chunk
    int tid  = threadIdx.x;
    int row0 = blockIdx.x * 64;

    // load A tile: h = g * (1/norm)
    for (int i = tid; i < 64 * (IN_DIM / 4); i += 256) {
        int r = i >> 5;            // IN_DIM/4 = 32 float4 per row
        int c = (i & 31) << 2;
        int row = row0 + r;
        float4 v = {0.f, 0.f, 0.f, 0.f};
        if (row < N) {
            v = *(const float4*)(g + (size_t)row * IN_DIM + c);
            float inv = 1.0f / norm[row];
            v.x *= inv; v.y *= inv; v.z *= inv; v.w *= inv;
        }
        Ah[r][c + 0] = v.x; Ah[r][c + 1] = v.y; Ah[r][c + 2] = v.z; Ah[r][c + 3] = v.w;
    }
    __syncthreads();

    int ty = tid >> 4;     // 0..15 -> 4 rows each
    int tx = tid & 15;     // 0..15
    int cb2 = tx * 8;

    float acc2[4][8];
    #pragma unroll
    for (int i = 0; i < 4; ++i)
        #pragma unroll
        for (int j = 0; j < 8; ++j) acc2[i][j] = 0.f;

    for (int ch = 0; ch < 4; ++ch) {
        // ---- GEMM1 chunk: Hc = relu(Ah @ W1[:, ch*64 .. +64] + b1) ----
        int colbase = ch * 64 + tx * 4;
        float acc[4][4];
        #pragma unroll
        for (int i = 0; i < 4; ++i)
            #pragma unroll
            for (int j = 0; j < 4; ++j) acc[i][j] = 0.f;

        for (int k = 0; k < IN_DIM; ++k) {
            float4 b = *(const float4*)(W1 + (size_t)k * HID_DIM + colbase);
            #pragma unroll
            for (int i = 0; i < 4; ++i) {
                float a = Ah[ty * 4 + i][k];
                acc[i][0] += a * b.x;
                acc[i][1] += a * b.y;
                acc[i][2] += a * b.z;
                acc[i][3] += a * b.w;
            }
        }
        float4 bias = *(const float4*)(b1 + ch * 64 + tx * 4);
        #pragma unroll
        for (int i = 0; i < 4; ++i) {
            float r0 = acc[i][0] + bias.x;
            float r1 = acc[i][1] + bias.y;
            float r2 = acc[i][2] + bias.z;
            float r3 = acc[i][3] + bias.w;
            Hc[ty * 4 + i][tx * 4 + 0] = r0 > 0.f ? r0 : 0.f;
            Hc[ty * 4 + i][tx * 4 + 1] = r1 > 0.f ? r1 : 0.f;
            Hc[ty * 4 + i][tx * 4 + 2] = r2 > 0.f ? r2 : 0.f;
            Hc[ty * 4 + i][tx * 4 + 3] = r3 > 0.f ? r3 : 0.f;
        }
        __syncthreads();

        // ---- GEMM2 partial: acc2 += Hc @ W2[ch*64 .. +64, :] ----
        for (int k2 = 0; k2 < 64; ++k2) {
            int k = ch * 64 + k2;
            float4 blo = *(const float4*)(W2 + (size_t)k * OUT_DIM + cb2);
            float4 bhi = *(const float4*)(W2 + (size_t)k * OUT_DIM + cb2 + 4);
            #pragma unroll
            for (int i = 0; i < 4; ++i) {
                float a = Hc[ty * 4 + i][k2];
                acc2[i][0] += a * blo.x;
                acc2[i][1] += a * blo.y;
                acc2[i][2] += a * blo.z;
                acc2[i][3] += a * blo.w;
                acc2[i][4] += a * bhi.x;
                acc2[i][5] += a * bhi.y;
                acc2[i][6] += a * bhi.z;
                acc2[i][7] += a * bhi.w;
            }
        }
        __syncthreads();   // protect Hc before next chunk's writes
    }

    float4 b2lo = *(const float4*)(b2 + cb2);
    float4 b2hi = *(const float4*)(b2 + cb2 + 4);
    #pragma unroll
    for (int i = 0; i < 4; ++i) {
        int row = row0 + ty * 4 + i;
        if (row < N) {
            float4 olo, ohi;
            olo.x = acc2[i][0] + b2lo.x;
            olo.y = acc2[i][1] + b2lo.y;
            olo.z = acc2[i][2] + b2lo.z;
            olo.w = acc2[i][3] + b2lo.w;
            ohi.x = acc2[i][4] + b2hi.x;
            ohi.y = acc2[i][5] + b2hi.y;
            ohi.z = acc2[i][6] + b2hi.z;
            ohi.w = acc2[i][7] + b2hi.w;
            *(float4*)(out + (size_t)row * OUT_DIM + cb2)     = olo;
            *(float4*)(out + (size_t)row * OUT_DIM + cb2 + 4) = ohi;
        }
    }
}

// ---------------- launch ----------------

extern "C" void kernel_launch(void* const* d_in, const int* in_sizes, int n_in,
                              void* d_out, int out_size, void* d_ws, size_t ws_size,
                              hipStream_t stream) {
    const float* feat = (const float*)d_in[0];
    const float* W1   = (const float*)d_in[1];
    const float* b1   = (const float*)d_in[2];
    const float* W2   = (const float*)d_in[3];
    const float* b2   = (const float*)d_in[4];
    const int*   src  = (const int*)d_in[5];
    const int*   dst  = (const int*)d_in[6];
    float* out = (float*)d_out;

    int N = in_sizes[0] / IN_DIM;     // 100000
    int E = in_sizes[5];              // 1600000

    // workspace carve (256B aligned)
    size_t off = 0;
    auto carve = [&](size_t bytes) -> void* {
        void* p = (char*)d_ws + off;
        off += (bytes + 255) & ~(size_t)255;
        return p;
    };
    float* norm    = (float*)carve((size_t)N * 4);
    int*   cnt     = (int*)carve((size_t)N * 4);
    int*   row_ptr = (int*)carve((size_t)(N + 1) * 4);
    int*   fill    = (int*)carve((size_t)N * 4);
    int*   bsum    = (int*)carve(512 * 4);
    int*   col     = (int*)carve((size_t)E * 4);
    float* gws     = (float*)carve((size_t)N * IN_DIM * 4);
    (void)ws_size;

    int nbN = (N + 255) / 256;        // 391
    int nbE = (E + 255) / 256;        // 6250

    count_init<<<nbN, 256, 0, stream>>>(cnt, fill, N);
    count_edges<<<nbE, 256, 0, stream>>>(dst, cnt, E);
    norm_kernel<<<nbN, 256, 0, stream>>>(cnt, norm, N);
    scan_block<<<nbN, 256, 0, stream>>>(cnt, row_ptr, bsum, N);
    scan_top<<<1, 512, 0, stream>>>(bsum, nbN);
    scan_add<<<nbN, 256, 0, stream>>>(row_ptr, bsum, N, E);
    fill_csr<<<nbE, 256, 0, stream>>>(src, dst, row_ptr, fill, col, E);

    int nbG = (N * (IN_DIM / 4) + 255) / 256;
    init_g<<<nbG, 256, 0, stream>>>(feat, norm, gws, N);

    // 2 nodes per wave -> 32 threads per node
    int nbHop = ((size_t)N * 32 + 255) / 256;
    for (int t = 0; t < KHOPS; ++t) {
        const float* gi = (t % 2 == 0) ? gws : out;
        float*       go = (t % 2 == 0) ? out : gws;
        hop_kernel<<<nbHop, 256, 0, stream>>>(gi, go, feat, norm, row_ptr, col, N);
    }
    // after 10 hops (even), final g is in gws

    int nbM = (N + 63) / 64;
    mlp_fused<<<nbM, 256, 0, stream>>>(gws, norm, W1, b1, W2, b2, out, N);
}